// Round 9
// baseline (1074.363 us; speedup 1.0000x reference)
//
#include <hip/hip_runtime.h>

#define NN 100000
#define NE 1600000
#define NB_SCAN 391   // ceil(NN/256)

// ---------------- bf16 helpers (manual, RNE) ----------------
__device__ inline float b2f(unsigned short u) {
  return __uint_as_float(((unsigned)u) << 16);
}
__device__ inline unsigned short f2b(float f) {
  unsigned x = __float_as_uint(f);
  unsigned r = (x + 0x7fffu + ((x >> 16) & 1u)) >> 16;
  return (unsigned short)r;
}
// packed u32 = 2 bf16 -> add into 2 floats; uint2 = 4 channels
__device__ inline void upadd(float4& a, uint2 u) {
  a.x += __uint_as_float(u.x << 16);
  a.y += __uint_as_float(u.x & 0xffff0000u);
  a.z += __uint_as_float(u.y << 16);
  a.w += __uint_as_float(u.y & 0xffff0000u);
}

// ---------------- CSR build ----------------

__global__ void count_rank_kernel(const int* __restrict__ dst, int* __restrict__ counts,
                                  int* __restrict__ rank) {
  int i = blockIdx.x * blockDim.x + threadIdx.x;
  int st = gridDim.x * blockDim.x;
  for (; i < NE; i += st) rank[i] = atomicAdd(&counts[dst[i]], 1);
}

__global__ void scan1_kernel(const int* __restrict__ counts, int* __restrict__ offsets,
                             int* __restrict__ blocksum, float* __restrict__ dinv) {
  __shared__ int s[256];
  int t = threadIdx.x;
  int i = blockIdx.x * 256 + t;
  int v = (i < NN) ? counts[i] : 0;
  s[t] = v; __syncthreads();
  for (int off = 1; off < 256; off <<= 1) {
    int x = 0;
    if (t >= off) x = s[t - off];
    __syncthreads();
    if (t >= off) s[t] += x;
    __syncthreads();
  }
  if (i < NN) {
    offsets[i] = s[t] - v;
    dinv[i] = rsqrtf((float)v + 1.0f);
  }
  if (t == 255) blocksum[blockIdx.x] = s[255];
}

__global__ void scan2_kernel(const int* __restrict__ blocksum, int* __restrict__ blockpfx,
                             int* __restrict__ offsets) {
  __shared__ int s[512];
  int t = threadIdx.x;
  int v = (t < NB_SCAN) ? blocksum[t] : 0;
  s[t] = v; __syncthreads();
  for (int off = 1; off < 512; off <<= 1) {
    int x = 0;
    if (t >= off) x = s[t - off];
    __syncthreads();
    if (t >= off) s[t] += x;
    __syncthreads();
  }
  if (t < NB_SCAN) blockpfx[t] = s[t] - v;
  if (t == 511) offsets[NN] = s[511];
}

__global__ void scan3_kernel(int* __restrict__ offsets, const int* __restrict__ blockpfx) {
  int i = blockIdx.x * 256 + threadIdx.x;
  if (i < NN) offsets[i] += blockpfx[i >> 8];
}

__global__ void scatter_kernel(const int* __restrict__ src, const int* __restrict__ dst,
                               const int* __restrict__ offsets, const int* __restrict__ rank,
                               int* __restrict__ src_s) {
  int i = blockIdx.x * blockDim.x + threadIdx.x;
  int st = gridDim.x * blockDim.x;
  for (; i < NE; i += st) {
    int d = dst[i];
    src_s[offsets[d] + rank[i]] = src[i];
  }
}

// ---------------- fold input Linear into layer-0 weight ----------------
__global__ void foldw_kernel(const float* __restrict__ W_in, const float* __restrict__ b_in,
                             const float* __restrict__ W0,
                             float* __restrict__ Wc, float* __restrict__ bc) {
  int t = threadIdx.x;
  for (int e = t; e < 4096; e += 256) {
    int i = e >> 6, j = e & 63;
    float s = 0.f;
#pragma unroll
    for (int k = 0; k < 64; ++k) s += W_in[i * 64 + k] * W0[k * 64 + j];
    Wc[e] = s;
  }
  if (t < 64) {
    float s = 0.f;
#pragma unroll
    for (int k = 0; k < 64; ++k) s += b_in[k] * W0[k * 64 + t];
    bc[t] = s;
  }
}

// ---------------- GEMM 64x64: broadcast-b128 LDS reads, fused affine-BN+ReLU, bf16 out ----
// block 256 = 4 waves; 16 rows/block; thread (col = t&63, rw = t>>6) does rows rw*4..+3.

__global__ __launch_bounds__(256) void gemm64_kernel(
    const float* __restrict__ x, const float* __restrict__ W, const float* __restrict__ bias,
    const float* __restrict__ bnac, const float* __restrict__ rowscale,
    unsigned short* __restrict__ out16) {
  __shared__ float sW[64][64];
  __shared__ float sx[16][64];
  int t = threadIdx.x;
  int col = t & 63;
  int rw = t >> 6;
  int row0 = blockIdx.x * 16;

#pragma unroll
  for (int j = 0; j < 16; ++j) {
    int e = t + 256 * j;
    sW[e >> 6][col] = W[e];
  }
  float a = 1.f, c = 0.f;
  if (bnac) { a = bnac[col]; c = bnac[64 + col]; }
#pragma unroll
  for (int j = 0; j < 4; ++j) {
    int e = t + 256 * j;
    int r = e >> 6;
    int grow = row0 + r;
    float v = (grow < NN) ? x[(size_t)grow * 64 + col] : 0.f;
    if (bnac) v = fmaxf(fmaf(v, a, c), 0.f);
    sx[r][col] = v;
  }
  __syncthreads();

  float acc0 = 0, acc1 = 0, acc2 = 0, acc3 = 0;
#pragma unroll 4
  for (int k = 0; k < 64; k += 4) {
    float4 x0 = *(const float4*)&sx[rw * 4 + 0][k];
    float4 x1 = *(const float4*)&sx[rw * 4 + 1][k];
    float4 x2 = *(const float4*)&sx[rw * 4 + 2][k];
    float4 x3 = *(const float4*)&sx[rw * 4 + 3][k];
    float w0 = sW[k + 0][col], w1 = sW[k + 1][col];
    float w2 = sW[k + 2][col], w3 = sW[k + 3][col];
    acc0 = fmaf(x0.w, w3, fmaf(x0.z, w2, fmaf(x0.y, w1, fmaf(x0.x, w0, acc0))));
    acc1 = fmaf(x1.w, w3, fmaf(x1.z, w2, fmaf(x1.y, w1, fmaf(x1.x, w0, acc1))));
    acc2 = fmaf(x2.w, w3, fmaf(x2.z, w2, fmaf(x2.y, w1, fmaf(x2.x, w0, acc2))));
    acc3 = fmaf(x3.w, w3, fmaf(x3.z, w2, fmaf(x3.y, w1, fmaf(x3.x, w0, acc3))));
  }
  float bv = bias ? bias[col] : 0.f;
  int r0 = row0 + rw * 4;
#pragma unroll
  for (int r = 0; r < 4; ++r) {
    int grow = r0 + r;
    if (grow < NN) {
      float acc = (r == 0) ? acc0 : (r == 1) ? acc1 : (r == 2) ? acc2 : acc3;
      out16[(size_t)grow * 64 + col] = f2b((acc + bv) * rowscale[grow]);
    }
  }
}

// ---------------- Edge aggregation: 4 edges per vmem (uint2 lanes), bias + BN stats ----
// One node per wave; lane: sub = lane&15 (4 channels), q = lane>>4 (edge slot).

__global__ __launch_bounds__(256) void agg_kernel(
    const uint2* __restrict__ xpu2, const int* __restrict__ offsets,
    const int* __restrict__ src_s, const float* __restrict__ dinv,
    const float* __restrict__ bvec, float4* __restrict__ h2f4,
    float* __restrict__ bnacc) {
  int t = threadIdx.x;
  int lane = t & 63;
  int wv = t >> 6;
  int sub = lane & 15;
  int q = lane >> 4;
  const float4 bias4 = ((const float4*)bvec)[sub];
  float4 s1 = make_float4(0, 0, 0, 0), s2 = make_float4(0, 0, 0, 0);
  int gw = blockIdx.x * 4 + wv;
  int nw = gridDim.x * 4;
  for (int n = gw; n < NN; n += nw) {
    int beg = offsets[n], end = offsets[n + 1];
    int deg = end - beg;
    float4 A = make_float4(0, 0, 0, 0), B = make_float4(0, 0, 0, 0);
    // self term (once: group 0 only)
    uint2 us = xpu2[(size_t)n * 16 + sub];
    if (q != 0) { us.x = 0; us.y = 0; }
    upadd(A, us);
    int done = 0;
    while (done < deg) {
      int chunk = deg - done;
      if (chunk > 64) chunk = 64;
      int idx = (lane < chunk) ? src_s[beg + done + lane] : 0;
      int full = chunk >> 2;
      int jj = 0;
      for (; jj + 4 <= full; jj += 4) {
        int i0 = __shfl(idx, (jj + 0) * 4 + q);
        int i1 = __shfl(idx, (jj + 1) * 4 + q);
        int i2 = __shfl(idx, (jj + 2) * 4 + q);
        int i3 = __shfl(idx, (jj + 3) * 4 + q);
        uint2 u0 = xpu2[(size_t)i0 * 16 + sub];
        uint2 u1 = xpu2[(size_t)i1 * 16 + sub];
        uint2 u2 = xpu2[(size_t)i2 * 16 + sub];
        uint2 u3 = xpu2[(size_t)i3 * 16 + sub];
        upadd(A, u0); upadd(B, u1); upadd(A, u2); upadd(B, u3);
      }
      for (; jj < full; ++jj) {
        int i0 = __shfl(idx, jj * 4 + q);
        uint2 u0 = xpu2[(size_t)i0 * 16 + sub];
        upadd(A, u0);
      }
      int rem = chunk & 3;
      if (rem) {
        int j = full * 4 + q;
        int i0 = __shfl(idx, (j < chunk) ? j : 0);
        uint2 u0 = xpu2[(size_t)i0 * 16 + sub];
        if (j >= chunk) { u0.x = 0; u0.y = 0; }
        upadd(A, u0);
      }
      done += chunk;
    }
    float4 acc = make_float4(A.x + B.x, A.y + B.y, A.z + B.z, A.w + B.w);
#pragma unroll
    for (int m = 16; m <= 32; m <<= 1) {
      acc.x += __shfl_xor(acc.x, m);
      acc.y += __shfl_xor(acc.y, m);
      acc.z += __shfl_xor(acc.z, m);
      acc.w += __shfl_xor(acc.w, m);
    }
    float di = dinv[n];
    float4 v = make_float4(fmaf(acc.x, di, bias4.x), fmaf(acc.y, di, bias4.y),
                           fmaf(acc.z, di, bias4.z), fmaf(acc.w, di, bias4.w));
    if (lane < 16) {
      h2f4[(size_t)n * 16 + sub] = v;
      s1.x += v.x; s1.y += v.y; s1.z += v.z; s1.w += v.w;
      s2.x += v.x * v.x; s2.y += v.y * v.y; s2.z += v.z * v.z; s2.w += v.w * v.w;
    }
  }
  __shared__ float4 ls[4][2][16];
  if (lane < 16) { ls[wv][0][sub] = s1; ls[wv][1][sub] = s2; }
  __syncthreads();
  if (t < 16) {
    float4 a = ls[0][0][t], b = ls[0][1][t];
#pragma unroll
    for (int w = 1; w < 4; ++w) {
      float4 x1 = ls[w][0][t], x2 = ls[w][1][t];
      a.x += x1.x; a.y += x1.y; a.z += x1.z; a.w += x1.w;
      b.x += x2.x; b.y += x2.y; b.z += x2.z; b.w += x2.w;
    }
    atomicAdd(&bnacc[t * 4 + 0], a.x);
    atomicAdd(&bnacc[t * 4 + 1], a.y);
    atomicAdd(&bnacc[t * 4 + 2], a.z);
    atomicAdd(&bnacc[t * 4 + 3], a.w);
    atomicAdd(&bnacc[64 + t * 4 + 0], b.x);
    atomicAdd(&bnacc[64 + t * 4 + 1], b.y);
    atomicAdd(&bnacc[64 + t * 4 + 2], b.z);
    atomicAdd(&bnacc[64 + t * 4 + 3], b.w);
  }
}

// BN finalize -> affine form: a = gamma*istd, c = beta - mean*a
__global__ void bn_finalize_kernel(const float* __restrict__ bnacc,
                                   const float* __restrict__ gamma,
                                   const float* __restrict__ beta,
                                   float* __restrict__ bnac) {
  int ch = threadIdx.x;  // 64 threads
  float mean = bnacc[ch] * (1.0f / NN);
  float var = bnacc[64 + ch] * (1.0f / NN) - mean * mean;
  float istd = rsqrtf(var + 1e-5f);
  float a = gamma[ch] * istd;
  bnac[ch] = a;
  bnac[64 + ch] = beta[ch] - mean * a;
}

// ---------------- Output MLP: affine-BN -> Linear(64,128)+ReLU -> Linear(128,1) ----------
// block 256; 16 rows/block. Phase1: thread (col=t&127, rg=t>>7) does 8 rows.
// Phase2: 16 threads per row reduce 128 cols.

__global__ __launch_bounds__(256) void out_kernel(
    const float* __restrict__ x, const float* __restrict__ bnac,
    const float* __restrict__ W1, const float* __restrict__ b1,
    const float* __restrict__ W2, const float* __restrict__ b2,
    float* __restrict__ out) {
  __shared__ float sW1[64][128];
  __shared__ float sx[16][64];
  __shared__ float sz[16][128];
  __shared__ float sW2[128];
  int t = threadIdx.x;
  int row0 = blockIdx.x * 16;
#pragma unroll
  for (int j = 0; j < 32; ++j) {
    int e = t + 256 * j;
    sW1[e >> 7][e & 127] = W1[e];
  }
  if (t < 128) sW2[t] = W2[t];
  {
    int c64 = t & 63;
    float a = bnac[c64], c = bnac[64 + c64];
#pragma unroll
    for (int j = 0; j < 4; ++j) {
      int e = t + 256 * j;
      int r = e >> 6;
      int grow = row0 + r;
      float v = (grow < NN) ? x[(size_t)grow * 64 + c64] : 0.f;
      sx[r][c64] = fmaf(v, a, c);   // BN, no ReLU (last layer)
    }
  }
  __syncthreads();

  int col = t & 127;
  int rg = t >> 7;
  float b1v = b1[col];
  float acc[8];
#pragma unroll
  for (int r = 0; r < 8; ++r) acc[r] = 0.f;
#pragma unroll 4
  for (int k = 0; k < 64; k += 4) {
    float w0 = sW1[k + 0][col], w1 = sW1[k + 1][col];
    float w2 = sW1[k + 2][col], w3 = sW1[k + 3][col];
#pragma unroll
    for (int r = 0; r < 8; ++r) {
      float4 xv = *(const float4*)&sx[rg * 8 + r][k];
      acc[r] = fmaf(xv.w, w3, fmaf(xv.z, w2, fmaf(xv.y, w1, fmaf(xv.x, w0, acc[r]))));
    }
  }
#pragma unroll
  for (int r = 0; r < 8; ++r) sz[rg * 8 + r][col] = fmaxf(acc[r] + b1v, 0.f);
  __syncthreads();

  {
    int row = t >> 4, g = t & 15;
    const float4* zr = (const float4*)&sz[row][0];
    const float4* wp = (const float4*)sW2;
    float4 z0 = zr[g * 2], z1 = zr[g * 2 + 1];
    float4 w0 = wp[g * 2], w1 = wp[g * 2 + 1];
    float p = z0.x * w0.x + z0.y * w0.y + z0.z * w0.z + z0.w * w0.w
            + z1.x * w1.x + z1.y * w1.y + z1.z * w1.z + z1.w * w1.w;
    p += __shfl_down(p, 8);
    p += __shfl_down(p, 4);
    p += __shfl_down(p, 2);
    p += __shfl_down(p, 1);
    int grow = row0 + row;
    if (g == 0 && grow < NN) out[grow] = p + b2[0];
  }
}

// ---------------- launch ----------------

extern "C" void kernel_launch(void* const* d_in, const int* in_sizes, int n_in,
                              void* d_out, int out_size, void* d_ws, size_t ws_size,
                              hipStream_t stream) {
  const float* X = (const float*)d_in[0];
  const int* edge = (const int*)d_in[1];
  const int* esrc = edge;
  const int* edst = edge + NE;
  const float* W_in = (const float*)d_in[2];
  const float* b_in = (const float*)d_in[3];
  const float* Ws = (const float*)d_in[4];
  const float* bs = (const float*)d_in[5];
  const float* gammas = (const float*)d_in[6];
  const float* betas = (const float*)d_in[7];
  const float* W1 = (const float*)d_in[8];
  const float* b1 = (const float*)d_in[9];
  const float* W2 = (const float*)d_in[10];
  const float* b2 = (const float*)d_in[11];
  float* out = (float*)d_out;

  char* base = (char*)d_ws;
  size_t o = 0;
  auto alloc = [&](size_t bytes) {
    o = (o + 255) & ~(size_t)255;
    void* p = base + o;
    o += bytes;
    return p;
  };
  int* counts = (int*)alloc((size_t)NN * 4);
  int* offsets = (int*)alloc((size_t)(NN + 1) * 4);
  int* blocksum = (int*)alloc(512 * 4);
  int* blockpfx = (int*)alloc(512 * 4);
  int* rank = (int*)alloc((size_t)NE * 4);
  int* src_s = (int*)alloc((size_t)NE * 4);
  float* dinv = (float*)alloc((size_t)NN * 4);
  float* bufA = (float*)alloc((size_t)NN * 64 * 4);
  float* bufB = (float*)alloc((size_t)NN * 64 * 4);
  unsigned short* hbuf16 = (unsigned short*)alloc((size_t)NN * 64 * 2);
  float* bnacc = (float*)alloc(3 * 128 * 4);
  float* bnpar = (float*)alloc(3 * 128 * 4);
  float* Wc = (float*)alloc(4096 * 4);
  float* bc = (float*)alloc(64 * 4);

  hipMemsetAsync(counts, 0, (size_t)NN * 4, stream);
  hipMemsetAsync(bnacc, 0, 3 * 128 * 4, stream);

  foldw_kernel<<<1, 256, 0, stream>>>(W_in, b_in, Ws, Wc, bc);
  count_rank_kernel<<<2048, 256, 0, stream>>>(edst, counts, rank);
  scan1_kernel<<<NB_SCAN, 256, 0, stream>>>(counts, offsets, blocksum, dinv);
  scan2_kernel<<<1, 512, 0, stream>>>(blocksum, blockpfx, offsets);
  scan3_kernel<<<NB_SCAN, 256, 0, stream>>>(offsets, blockpfx);
  scatter_kernel<<<2048, 256, 0, stream>>>(esrc, edst, offsets, rank, src_s);

  const int GEMM_GRID = (NN + 15) / 16;   // 6250
  float* xbufs[2] = {bufA, bufB};
  const float* xcur = nullptr;
  for (int i = 0; i < 3; ++i) {
    if (i == 0) {
      gemm64_kernel<<<GEMM_GRID, 256, 0, stream>>>(X, Wc, bc, nullptr, dinv, hbuf16);
    } else {
      gemm64_kernel<<<GEMM_GRID, 256, 0, stream>>>(xcur, Ws + (size_t)i * 64 * 64, nullptr,
                                                   bnpar + (size_t)(i - 1) * 128,
                                                   dinv, hbuf16);
    }
    float* xnext = xbufs[i & 1];
    agg_kernel<<<2048, 256, 0, stream>>>((const uint2*)hbuf16, offsets, src_s, dinv,
                                         bs + (size_t)i * 64, (float4*)xnext,
                                         bnacc + (size_t)i * 128);
    bn_finalize_kernel<<<1, 64, 0, stream>>>(bnacc + (size_t)i * 128,
                                             gammas + (size_t)i * 64,
                                             betas + (size_t)i * 64,
                                             bnpar + (size_t)i * 128);
    xcur = xnext;
  }
  out_kernel<<<GEMM_GRID, 256, 0, stream>>>(xcur, bnpar + 2 * 128, W1, b1, W2, b2, out);
}

// Round 10
// 629.662 us; speedup vs baseline: 1.7063x; 1.7063x over previous
//
#include <hip/hip_runtime.h>

#define NN 100000
#define NE 1600000
#define NB_SCAN 391   // ceil(NN/256)

// ---------------- bf16 helpers (manual, RNE) ----------------
__device__ inline float b2f(unsigned short u) {
  return __uint_as_float(((unsigned)u) << 16);
}
__device__ inline unsigned short f2b(float f) {
  unsigned x = __float_as_uint(f);
  unsigned r = (x + 0x7fffu + ((x >> 16) & 1u)) >> 16;
  return (unsigned short)r;
}

// ---------------- CSR build ----------------

__global__ void count_rank_kernel(const int* __restrict__ dst, int* __restrict__ counts,
                                  int* __restrict__ rank) {
  int i = blockIdx.x * blockDim.x + threadIdx.x;
  int st = gridDim.x * blockDim.x;
  for (; i < NE; i += st) rank[i] = atomicAdd(&counts[dst[i]], 1);
}

__global__ void scan1_kernel(const int* __restrict__ counts, int* __restrict__ offsets,
                             int* __restrict__ blocksum, float* __restrict__ dinv) {
  __shared__ int s[256];
  int t = threadIdx.x;
  int i = blockIdx.x * 256 + t;
  int v = (i < NN) ? counts[i] : 0;
  s[t] = v; __syncthreads();
  for (int off = 1; off < 256; off <<= 1) {
    int x = 0;
    if (t >= off) x = s[t - off];
    __syncthreads();
    if (t >= off) s[t] += x;
    __syncthreads();
  }
  if (i < NN) {
    offsets[i] = s[t] - v;
    dinv[i] = rsqrtf((float)v + 1.0f);
  }
  if (t == 255) blocksum[blockIdx.x] = s[255];
}

__global__ void scan2_kernel(const int* __restrict__ blocksum, int* __restrict__ blockpfx,
                             int* __restrict__ offsets) {
  __shared__ int s[512];
  int t = threadIdx.x;
  int v = (t < NB_SCAN) ? blocksum[t] : 0;
  s[t] = v; __syncthreads();
  for (int off = 1; off < 512; off <<= 1) {
    int x = 0;
    if (t >= off) x = s[t - off];
    __syncthreads();
    if (t >= off) s[t] += x;
    __syncthreads();
  }
  if (t < NB_SCAN) blockpfx[t] = s[t] - v;
  if (t == 511) offsets[NN] = s[511];
}

__global__ void scan3_kernel(int* __restrict__ offsets, const int* __restrict__ blockpfx) {
  int i = blockIdx.x * 256 + threadIdx.x;
  if (i < NN) offsets[i] += blockpfx[i >> 8];
}

__global__ void scatter_kernel(const int* __restrict__ src, const int* __restrict__ dst,
                               const int* __restrict__ offsets, const int* __restrict__ rank,
                               int* __restrict__ src_s) {
  int i = blockIdx.x * blockDim.x + threadIdx.x;
  int st = gridDim.x * blockDim.x;
  for (; i < NE; i += st) {
    int d = dst[i];
    src_s[offsets[d] + rank[i]] = src[i];
  }
}

// ---------------- fold input Linear into layer-0 weight ----------------
__global__ void foldw_kernel(const float* __restrict__ W_in, const float* __restrict__ b_in,
                             const float* __restrict__ W0,
                             float* __restrict__ Wc, float* __restrict__ bc) {
  int t = threadIdx.x;
  for (int e = t; e < 4096; e += 256) {
    int i = e >> 6, j = e & 63;
    float s = 0.f;
#pragma unroll
    for (int k = 0; k < 64; ++k) s += W_in[i * 64 + k] * W0[k * 64 + j];
    Wc[e] = s;
  }
  if (t < 64) {
    float s = 0.f;
#pragma unroll
    for (int k = 0; k < 64; ++k) s += b_in[k] * W0[k * 64 + t];
    bc[t] = s;
  }
}

// ---------------- GEMM 64x64: broadcast-b128 LDS reads, fused affine-BN+ReLU, bf16 out ----

__global__ __launch_bounds__(256) void gemm64_kernel(
    const float* __restrict__ x, const float* __restrict__ W, const float* __restrict__ bias,
    const float* __restrict__ bnac, const float* __restrict__ rowscale,
    unsigned short* __restrict__ out16) {
  __shared__ float sW[64][64];
  __shared__ float sx[16][64];
  int t = threadIdx.x;
  int col = t & 63;
  int rw = t >> 6;
  int row0 = blockIdx.x * 16;

#pragma unroll
  for (int j = 0; j < 16; ++j) {
    int e = t + 256 * j;
    sW[e >> 6][col] = W[e];
  }
  float a = 1.f, c = 0.f;
  if (bnac) { a = bnac[col]; c = bnac[64 + col]; }
#pragma unroll
  for (int j = 0; j < 4; ++j) {
    int e = t + 256 * j;
    int r = e >> 6;
    int grow = row0 + r;
    float v = (grow < NN) ? x[(size_t)grow * 64 + col] : 0.f;
    if (bnac) v = fmaxf(fmaf(v, a, c), 0.f);
    sx[r][col] = v;
  }
  __syncthreads();

  float acc0 = 0, acc1 = 0, acc2 = 0, acc3 = 0;
#pragma unroll 4
  for (int k = 0; k < 64; k += 4) {
    float4 x0 = *(const float4*)&sx[rw * 4 + 0][k];
    float4 x1 = *(const float4*)&sx[rw * 4 + 1][k];
    float4 x2 = *(const float4*)&sx[rw * 4 + 2][k];
    float4 x3 = *(const float4*)&sx[rw * 4 + 3][k];
    float w0 = sW[k + 0][col], w1 = sW[k + 1][col];
    float w2 = sW[k + 2][col], w3 = sW[k + 3][col];
    acc0 = fmaf(x0.w, w3, fmaf(x0.z, w2, fmaf(x0.y, w1, fmaf(x0.x, w0, acc0))));
    acc1 = fmaf(x1.w, w3, fmaf(x1.z, w2, fmaf(x1.y, w1, fmaf(x1.x, w0, acc1))));
    acc2 = fmaf(x2.w, w3, fmaf(x2.z, w2, fmaf(x2.y, w1, fmaf(x2.x, w0, acc2))));
    acc3 = fmaf(x3.w, w3, fmaf(x3.z, w2, fmaf(x3.y, w1, fmaf(x3.x, w0, acc3))));
  }
  float bv = bias ? bias[col] : 0.f;
  int r0 = row0 + rw * 4;
#pragma unroll
  for (int r = 0; r < 4; ++r) {
    int grow = r0 + r;
    if (grow < NN) {
      float acc = (r == 0) ? acc0 : (r == 1) ? acc1 : (r == 2) ? acc2 : acc3;
      out16[(size_t)grow * 64 + col] = f2b((acc + bv) * rowscale[grow]);
    }
  }
}

// ---------------- Edge aggregation: 2 nodes/wave interleaved, 16 gathers in flight ----

__device__ __forceinline__ void agg_slow(const unsigned short* __restrict__ xp16,
                                         const int* __restrict__ src_s,
                                         int beg, int end, int lane,
                                         float& a0, float& a1, float& a2, float& a3) {
  int deg = end - beg, done = 0;
  while (done < deg) {
    int chunk = deg - done;
    if (chunk > 64) chunk = 64;
    int idx = (lane < chunk) ? src_s[beg + done + lane] : 0;
    int j = 0;
    for (; j + 4 <= chunk; j += 4) {
      int t0 = __shfl(idx, j + 0), t1 = __shfl(idx, j + 1);
      int t2 = __shfl(idx, j + 2), t3 = __shfl(idx, j + 3);
      a0 += b2f(xp16[(size_t)t0 * 64 + lane]);
      a1 += b2f(xp16[(size_t)t1 * 64 + lane]);
      a2 += b2f(xp16[(size_t)t2 * 64 + lane]);
      a3 += b2f(xp16[(size_t)t3 * 64 + lane]);
    }
    for (; j < chunk; ++j) {
      int s = __shfl(idx, j);
      a0 += b2f(xp16[(size_t)s * 64 + lane]);
    }
    done += chunk;
  }
}

__global__ __launch_bounds__(256) void agg_kernel(
    const unsigned short* __restrict__ xp16, const int* __restrict__ offsets,
    const int* __restrict__ src_s, const float* __restrict__ dinv,
    const float* __restrict__ bvec, float* __restrict__ h2,
    float* __restrict__ bnacc) {
  int t = threadIdx.x;
  int lane = t & 63;
  int wv = t >> 6;
  float bias = bvec[lane];
  float s1 = 0.f, s2 = 0.f;
  int gw = blockIdx.x * 4 + wv;
  int nw = gridDim.x * 4;
  const int NP = NN / 2;   // 50000 pairs (NN even)
  for (int p = gw; p < NP; p += nw) {
    int nA = 2 * p, nB = 2 * p + 1;
    int begA = offsets[nA];
    int begB = offsets[nA + 1];
    int endB = offsets[nA + 2];
    int degA = begB - begA, degB = endB - begB;
    float a0 = b2f(xp16[(size_t)nA * 64 + lane]), a1 = 0.f, a2 = 0.f, a3 = 0.f;
    float c0 = b2f(xp16[(size_t)nB * 64 + lane]), c1 = 0.f, c2 = 0.f, c3 = 0.f;
    if (degA <= 64 && degB <= 64) {
      int idxA = (lane < degA) ? src_s[begA + lane] : 0;
      int idxB = (lane < degB) ? src_s[begB + lane] : 0;
      int ja = 0, jb = 0;
      // interleaved: 8 from A + 8 from B per iteration -> 16 loads in flight
      while (ja + 8 <= degA && jb + 8 <= degB) {
        int A0 = __shfl(idxA, ja + 0), A1 = __shfl(idxA, ja + 1);
        int A2 = __shfl(idxA, ja + 2), A3 = __shfl(idxA, ja + 3);
        int A4 = __shfl(idxA, ja + 4), A5 = __shfl(idxA, ja + 5);
        int A6 = __shfl(idxA, ja + 6), A7 = __shfl(idxA, ja + 7);
        int B0 = __shfl(idxB, jb + 0), B1 = __shfl(idxB, jb + 1);
        int B2 = __shfl(idxB, jb + 2), B3 = __shfl(idxB, jb + 3);
        int B4 = __shfl(idxB, jb + 4), B5 = __shfl(idxB, jb + 5);
        int B6 = __shfl(idxB, jb + 6), B7 = __shfl(idxB, jb + 7);
        unsigned short uA0 = xp16[(size_t)A0 * 64 + lane];
        unsigned short uA1 = xp16[(size_t)A1 * 64 + lane];
        unsigned short uA2 = xp16[(size_t)A2 * 64 + lane];
        unsigned short uA3 = xp16[(size_t)A3 * 64 + lane];
        unsigned short uA4 = xp16[(size_t)A4 * 64 + lane];
        unsigned short uA5 = xp16[(size_t)A5 * 64 + lane];
        unsigned short uA6 = xp16[(size_t)A6 * 64 + lane];
        unsigned short uA7 = xp16[(size_t)A7 * 64 + lane];
        unsigned short uB0 = xp16[(size_t)B0 * 64 + lane];
        unsigned short uB1 = xp16[(size_t)B1 * 64 + lane];
        unsigned short uB2 = xp16[(size_t)B2 * 64 + lane];
        unsigned short uB3 = xp16[(size_t)B3 * 64 + lane];
        unsigned short uB4 = xp16[(size_t)B4 * 64 + lane];
        unsigned short uB5 = xp16[(size_t)B5 * 64 + lane];
        unsigned short uB6 = xp16[(size_t)B6 * 64 + lane];
        unsigned short uB7 = xp16[(size_t)B7 * 64 + lane];
        a0 += b2f(uA0) + b2f(uA4);  a1 += b2f(uA1) + b2f(uA5);
        a2 += b2f(uA2) + b2f(uA6);  a3 += b2f(uA3) + b2f(uA7);
        c0 += b2f(uB0) + b2f(uB4);  c1 += b2f(uB1) + b2f(uB5);
        c2 += b2f(uB2) + b2f(uB6);  c3 += b2f(uB3) + b2f(uB7);
        ja += 8; jb += 8;
      }
      // drain A
      for (; ja + 8 <= degA; ja += 8) {
        int A0 = __shfl(idxA, ja + 0), A1 = __shfl(idxA, ja + 1);
        int A2 = __shfl(idxA, ja + 2), A3 = __shfl(idxA, ja + 3);
        int A4 = __shfl(idxA, ja + 4), A5 = __shfl(idxA, ja + 5);
        int A6 = __shfl(idxA, ja + 6), A7 = __shfl(idxA, ja + 7);
        unsigned short u0 = xp16[(size_t)A0 * 64 + lane];
        unsigned short u1 = xp16[(size_t)A1 * 64 + lane];
        unsigned short u2 = xp16[(size_t)A2 * 64 + lane];
        unsigned short u3 = xp16[(size_t)A3 * 64 + lane];
        unsigned short u4 = xp16[(size_t)A4 * 64 + lane];
        unsigned short u5 = xp16[(size_t)A5 * 64 + lane];
        unsigned short u6 = xp16[(size_t)A6 * 64 + lane];
        unsigned short u7 = xp16[(size_t)A7 * 64 + lane];
        a0 += b2f(u0) + b2f(u4);  a1 += b2f(u1) + b2f(u5);
        a2 += b2f(u2) + b2f(u6);  a3 += b2f(u3) + b2f(u7);
      }
      for (; ja + 4 <= degA; ja += 4) {
        int A0 = __shfl(idxA, ja + 0), A1 = __shfl(idxA, ja + 1);
        int A2 = __shfl(idxA, ja + 2), A3 = __shfl(idxA, ja + 3);
        a0 += b2f(xp16[(size_t)A0 * 64 + lane]);
        a1 += b2f(xp16[(size_t)A1 * 64 + lane]);
        a2 += b2f(xp16[(size_t)A2 * 64 + lane]);
        a3 += b2f(xp16[(size_t)A3 * 64 + lane]);
      }
      for (; ja < degA; ++ja) {
        int s = __shfl(idxA, ja);
        a0 += b2f(xp16[(size_t)s * 64 + lane]);
      }
      // drain B
      for (; jb + 8 <= degB; jb += 8) {
        int B0 = __shfl(idxB, jb + 0), B1 = __shfl(idxB, jb + 1);
        int B2 = __shfl(idxB, jb + 2), B3 = __shfl(idxB, jb + 3);
        int B4 = __shfl(idxB, jb + 4), B5 = __shfl(idxB, jb + 5);
        int B6 = __shfl(idxB, jb + 6), B7 = __shfl(idxB, jb + 7);
        unsigned short u0 = xp16[(size_t)B0 * 64 + lane];
        unsigned short u1 = xp16[(size_t)B1 * 64 + lane];
        unsigned short u2 = xp16[(size_t)B2 * 64 + lane];
        unsigned short u3 = xp16[(size_t)B3 * 64 + lane];
        unsigned short u4 = xp16[(size_t)B4 * 64 + lane];
        unsigned short u5 = xp16[(size_t)B5 * 64 + lane];
        unsigned short u6 = xp16[(size_t)B6 * 64 + lane];
        unsigned short u7 = xp16[(size_t)B7 * 64 + lane];
        c0 += b2f(u0) + b2f(u4);  c1 += b2f(u1) + b2f(u5);
        c2 += b2f(u2) + b2f(u6);  c3 += b2f(u3) + b2f(u7);
      }
      for (; jb + 4 <= degB; jb += 4) {
        int B0 = __shfl(idxB, jb + 0), B1 = __shfl(idxB, jb + 1);
        int B2 = __shfl(idxB, jb + 2), B3 = __shfl(idxB, jb + 3);
        c0 += b2f(xp16[(size_t)B0 * 64 + lane]);
        c1 += b2f(xp16[(size_t)B1 * 64 + lane]);
        c2 += b2f(xp16[(size_t)B2 * 64 + lane]);
        c3 += b2f(xp16[(size_t)B3 * 64 + lane]);
      }
      for (; jb < degB; ++jb) {
        int s = __shfl(idxB, jb);
        c0 += b2f(xp16[(size_t)s * 64 + lane]);
      }
    } else {
      agg_slow(xp16, src_s, begA, begB, lane, a0, a1, a2, a3);
      agg_slow(xp16, src_s, begB, endB, lane, c0, c1, c2, c3);
    }
    float vA = ((a0 + a1) + (a2 + a3)) * dinv[nA] + bias;
    float vB = ((c0 + c1) + (c2 + c3)) * dinv[nB] + bias;
    h2[(size_t)nA * 64 + lane] = vA;
    h2[(size_t)nB * 64 + lane] = vB;
    s1 += vA + vB;
    s2 += vA * vA + vB * vB;
  }
  __shared__ float ls[4][2][64];
  ls[wv][0][lane] = s1;
  ls[wv][1][lane] = s2;
  __syncthreads();
  if (wv == 0) {
    float a = ls[0][0][lane] + ls[1][0][lane] + ls[2][0][lane] + ls[3][0][lane];
    float b = ls[0][1][lane] + ls[1][1][lane] + ls[2][1][lane] + ls[3][1][lane];
    atomicAdd(&bnacc[lane], a);
    atomicAdd(&bnacc[64 + lane], b);
  }
}

// BN finalize -> affine form: a = gamma*istd, c = beta - mean*a
__global__ void bn_finalize_kernel(const float* __restrict__ bnacc,
                                   const float* __restrict__ gamma,
                                   const float* __restrict__ beta,
                                   float* __restrict__ bnac) {
  int ch = threadIdx.x;  // 64 threads
  float mean = bnacc[ch] * (1.0f / NN);
  float var = bnacc[64 + ch] * (1.0f / NN) - mean * mean;
  float istd = rsqrtf(var + 1e-5f);
  float a = gamma[ch] * istd;
  bnac[ch] = a;
  bnac[64 + ch] = beta[ch] - mean * a;
}

// ---------------- Output MLP: affine-BN -> Linear(64,128)+ReLU -> Linear(128,1) ----------

__global__ __launch_bounds__(256) void out_kernel(
    const float* __restrict__ x, const float* __restrict__ bnac,
    const float* __restrict__ W1, const float* __restrict__ b1,
    const float* __restrict__ W2, const float* __restrict__ b2,
    float* __restrict__ out) {
  __shared__ float sW1[64][128];
  __shared__ float sx[16][64];
  __shared__ float sz[16][128];
  __shared__ float sW2[128];
  int t = threadIdx.x;
  int row0 = blockIdx.x * 16;
#pragma unroll
  for (int j = 0; j < 32; ++j) {
    int e = t + 256 * j;
    sW1[e >> 7][e & 127] = W1[e];
  }
  if (t < 128) sW2[t] = W2[t];
  {
    int c64 = t & 63;
    float a = bnac[c64], c = bnac[64 + c64];
#pragma unroll
    for (int j = 0; j < 4; ++j) {
      int e = t + 256 * j;
      int r = e >> 6;
      int grow = row0 + r;
      float v = (grow < NN) ? x[(size_t)grow * 64 + c64] : 0.f;
      sx[r][c64] = fmaf(v, a, c);   // BN, no ReLU (last layer)
    }
  }
  __syncthreads();

  int col = t & 127;
  int rg = t >> 7;
  float b1v = b1[col];
  float acc[8];
#pragma unroll
  for (int r = 0; r < 8; ++r) acc[r] = 0.f;
#pragma unroll 4
  for (int k = 0; k < 64; k += 4) {
    float w0 = sW1[k + 0][col], w1 = sW1[k + 1][col];
    float w2 = sW1[k + 2][col], w3 = sW1[k + 3][col];
#pragma unroll
    for (int r = 0; r < 8; ++r) {
      float4 xv = *(const float4*)&sx[rg * 8 + r][k];
      acc[r] = fmaf(xv.w, w3, fmaf(xv.z, w2, fmaf(xv.y, w1, fmaf(xv.x, w0, acc[r]))));
    }
  }
#pragma unroll
  for (int r = 0; r < 8; ++r) sz[rg * 8 + r][col] = fmaxf(acc[r] + b1v, 0.f);
  __syncthreads();

  {
    int row = t >> 4, g = t & 15;
    const float4* zr = (const float4*)&sz[row][0];
    const float4* wp = (const float4*)sW2;
    float4 z0 = zr[g * 2], z1 = zr[g * 2 + 1];
    float4 w0 = wp[g * 2], w1 = wp[g * 2 + 1];
    float p = z0.x * w0.x + z0.y * w0.y + z0.z * w0.z + z0.w * w0.w
            + z1.x * w1.x + z1.y * w1.y + z1.z * w1.z + z1.w * w1.w;
    p += __shfl_down(p, 8);
    p += __shfl_down(p, 4);
    p += __shfl_down(p, 2);
    p += __shfl_down(p, 1);
    int grow = row0 + row;
    if (g == 0 && grow < NN) out[grow] = p + b2[0];
  }
}

// ---------------- launch ----------------

extern "C" void kernel_launch(void* const* d_in, const int* in_sizes, int n_in,
                              void* d_out, int out_size, void* d_ws, size_t ws_size,
                              hipStream_t stream) {
  const float* X = (const float*)d_in[0];
  const int* edge = (const int*)d_in[1];
  const int* esrc = edge;
  const int* edst = edge + NE;
  const float* W_in = (const float*)d_in[2];
  const float* b_in = (const float*)d_in[3];
  const float* Ws = (const float*)d_in[4];
  const float* bs = (const float*)d_in[5];
  const float* gammas = (const float*)d_in[6];
  const float* betas = (const float*)d_in[7];
  const float* W1 = (const float*)d_in[8];
  const float* b1 = (const float*)d_in[9];
  const float* W2 = (const float*)d_in[10];
  const float* b2 = (const float*)d_in[11];
  float* out = (float*)d_out;

  char* base = (char*)d_ws;
  size_t o = 0;
  auto alloc = [&](size_t bytes) {
    o = (o + 255) & ~(size_t)255;
    void* p = base + o;
    o += bytes;
    return p;
  };
  int* counts = (int*)alloc((size_t)NN * 4);
  int* offsets = (int*)alloc((size_t)(NN + 1) * 4);
  int* blocksum = (int*)alloc(512 * 4);
  int* blockpfx = (int*)alloc(512 * 4);
  int* rank = (int*)alloc((size_t)NE * 4);
  int* src_s = (int*)alloc((size_t)NE * 4);
  float* dinv = (float*)alloc((size_t)NN * 4);
  float* bufA = (float*)alloc((size_t)NN * 64 * 4);
  float* bufB = (float*)alloc((size_t)NN * 64 * 4);
  unsigned short* hbuf16 = (unsigned short*)alloc((size_t)NN * 64 * 2);
  float* bnacc = (float*)alloc(3 * 128 * 4);
  float* bnpar = (float*)alloc(3 * 128 * 4);
  float* Wc = (float*)alloc(4096 * 4);
  float* bc = (float*)alloc(64 * 4);

  hipMemsetAsync(counts, 0, (size_t)NN * 4, stream);
  hipMemsetAsync(bnacc, 0, 3 * 128 * 4, stream);

  foldw_kernel<<<1, 256, 0, stream>>>(W_in, b_in, Ws, Wc, bc);
  count_rank_kernel<<<2048, 256, 0, stream>>>(edst, counts, rank);
  scan1_kernel<<<NB_SCAN, 256, 0, stream>>>(counts, offsets, blocksum, dinv);
  scan2_kernel<<<1, 512, 0, stream>>>(blocksum, blockpfx, offsets);
  scan3_kernel<<<NB_SCAN, 256, 0, stream>>>(offsets, blockpfx);
  scatter_kernel<<<2048, 256, 0, stream>>>(esrc, edst, offsets, rank, src_s);

  const int GEMM_GRID = (NN + 15) / 16;   // 6250
  float* xbufs[2] = {bufA, bufB};
  const float* xcur = nullptr;
  for (int i = 0; i < 3; ++i) {
    if (i == 0) {
      gemm64_kernel<<<GEMM_GRID, 256, 0, stream>>>(X, Wc, bc, nullptr, dinv, hbuf16);
    } else {
      gemm64_kernel<<<GEMM_GRID, 256, 0, stream>>>(xcur, Ws + (size_t)i * 64 * 64, nullptr,
                                                   bnpar + (size_t)(i - 1) * 128,
                                                   dinv, hbuf16);
    }
    float* xnext = xbufs[i & 1];
    agg_kernel<<<2048, 256, 0, stream>>>(hbuf16, offsets, src_s, dinv,
                                         bs + (size_t)i * 64, xnext,
                                         bnacc + (size_t)i * 128);
    bn_finalize_kernel<<<1, 64, 0, stream>>>(bnacc + (size_t)i * 128,
                                             gammas + (size_t)i * 64,
                                             betas + (size_t)i * 64,
                                             bnpar + (size_t)i * 128);
    xcur = xnext;
  }
  out_kernel<<<GEMM_GRID, 256, 0, stream>>>(xcur, bnpar + 2 * 128, W1, b1, W2, b2, out);
}